// Round 6
// baseline (284.350 us; speedup 1.0000x reference)
//
#include <hip/hip_runtime.h>

// ---------------------------------------------------------------------------
// GNN 2-layer via bf16 MFMA + CSR gather (no atomics in hot path).
//   m1 = bf16(X @ W1 + b1)            [MFMA, fp32 acc]
//   agg1 = bf16(seg_sum m1[src])      [gather, quad-split, 16 rows MLP]
//   m2 = [agg1,m1] @ W2 + b2          [MFMA] -> out[:,128:] fp32 + bf16 copy
//   agg2 = seg_sum m2[src]            [gather] -> out[:,:128] fp32
// CSR build is XCD-partitioned via REAL XCC_ID + per-XCD work queues with
// stealing: block claims (range = its own XCD, chunk); deg/cnt atomics and
// bsrc writes for a range stay in ONE XCD's L2 (no cross-XCD line ping-pong).
// ws: m1bf | agg1bf | m2bf | W1p | W2p | qh | qf | deg | cnt | offs | ... | bsrc
// ---------------------------------------------------------------------------

#define D 128
#define NCHUNK 256   // edge chunks per dst-range

typedef __attribute__((ext_vector_type(8))) short short8;
typedef __attribute__((ext_vector_type(4))) float float4v;
typedef unsigned short ushort_t;
typedef unsigned int uint_t;

static __device__ __forceinline__ ushort_t f2bf(float f) {
    uint_t u = __builtin_bit_cast(uint_t, f);
    u += 0x7FFFu + ((u >> 16) & 1u);           // RNE
    return (ushort_t)(u >> 16);
}
static __device__ __forceinline__ float bfhi(uint_t u) {
    return __builtin_bit_cast(float, u & 0xFFFF0000u);
}
static __device__ __forceinline__ float bflo(uint_t u) {
    return __builtin_bit_cast(float, u << 16);
}
static __device__ __forceinline__ int xcc_id() {
    int x;
    asm volatile("s_getreg_b32 %0, hwreg(HW_REG_XCC_ID)" : "=s"(x));
    return x & 7;
}

// ---------------- pack W (B-fragment layout) + zero CSR scratch -------------
// frag for (kb, cg, lane): 8 bf16 = W[kb*32 + (lane>>4)*8 + j][cg*16 + (lane&15)]
__global__ __launch_bounds__(256) void pack_zero(const float* __restrict__ W1,
                                                 const float* __restrict__ W2,
                                                 ushort_t* __restrict__ W1p,
                                                 ushort_t* __restrict__ W2p,
                                                 int* __restrict__ zbase, int nz) {
    const int n1 = 4 * 8 * 64;
    const int n2 = 8 * 8 * 64;
    int t = blockIdx.x * 256 + threadIdx.x;
    if (t < nz) zbase[t] = 0;
    if (t >= n1 + n2) return;
    const float* W; ushort_t* Wp; int tt;
    if (t < n1) { W = W1; Wp = W1p; tt = t; }
    else        { W = W2; Wp = W2p; tt = t - n1; }
    int lane = tt & 63, cg = (tt >> 6) & 7, kb = tt >> 9;
    int krow = kb * 32 + (lane >> 4) * 8;
    int col  = cg * 16 + (lane & 15);
    #pragma unroll
    for (int j = 0; j < 8; ++j)
        Wp[(size_t)tt * 8 + j] = f2bf(W[(size_t)(krow + j) * D + col]);
}

// ---------------- CSR build: XCD-local hist + fill via work queues ----------
__global__ __launch_bounds__(256) void hist_xcd(const int* __restrict__ dst,
                                                int* __restrict__ deg,
                                                int* __restrict__ queue,  // 8 counters, stride 32
                                                int E, int N) {
    __shared__ int sChunk;
    const int x = xcc_id();
    const int chunk = (E + NCHUNK - 1) / NCHUNK;
    for (int t = 0; t < 8; ++t) {
        int q = (x + t) & 7;                    // own queue first, then steal
        int lo = (int)((long long)N * q >> 3);
        int hi = (int)((long long)N * (q + 1) >> 3);
        for (;;) {
            __syncthreads();
            if (threadIdx.x == 0) sChunk = atomicAdd(&queue[q * 32], 1);
            __syncthreads();
            int c = sChunk;
            if (c >= NCHUNK) break;
            int e0 = c * chunk;
            int e1 = e0 + chunk; if (e1 > E) e1 = E;
            for (int e = e0 + threadIdx.x; e < e1; e += 256) {
                int d = dst[e];
                if (d >= lo && d < hi) atomicAdd(&deg[d], 1);
            }
        }
    }
}

__global__ __launch_bounds__(256) void fill_xcd(const int* __restrict__ src,
                                                const int* __restrict__ dst,
                                                const int* __restrict__ offs,
                                                int* __restrict__ cnt,
                                                int* __restrict__ bsrc,
                                                int* __restrict__ queue,
                                                int E, int N) {
    __shared__ int sChunk;
    const int x = xcc_id();
    const int chunk = (E + NCHUNK - 1) / NCHUNK;
    for (int t = 0; t < 8; ++t) {
        int q = (x + t) & 7;
        int lo = (int)((long long)N * q >> 3);
        int hi = (int)((long long)N * (q + 1) >> 3);
        for (;;) {
            __syncthreads();
            if (threadIdx.x == 0) sChunk = atomicAdd(&queue[q * 32], 1);
            __syncthreads();
            int c = sChunk;
            if (c >= NCHUNK) break;
            int e0 = c * chunk;
            int e1 = e0 + chunk; if (e1 > E) e1 = E;
            for (int e = e0 + threadIdx.x; e < e1; e += 256) {
                int d = dst[e];
                if (d >= lo && d < hi) {
                    int p = offs[d] + atomicAdd(&cnt[d], 1);
                    bsrc[p] = src[e];
                }
            }
        }
    }
}

// ---------------- scans ----------------------------------------------------
__global__ __launch_bounds__(256) void scan1_kernel(const int* __restrict__ deg,
                                                    int* __restrict__ offs,
                                                    int* __restrict__ bsums, int N) {
    __shared__ int s[256];
    int tid = threadIdx.x;
    int i = blockIdx.x * 256 + tid;
    int v = (i < N) ? deg[i] : 0;
    s[tid] = v; __syncthreads();
    for (int o = 1; o < 256; o <<= 1) {
        int t = (tid >= o) ? s[tid - o] : 0;
        __syncthreads();
        s[tid] += t;
        __syncthreads();
    }
    if (i < N) offs[i] = s[tid] - v;
    if (tid == 255) bsums[blockIdx.x] = s[255];
}

__global__ __launch_bounds__(256) void scan2_kernel(const int* __restrict__ bsums,
                                                    int* __restrict__ boffs, int nb,
                                                    int* __restrict__ offs, int N) {
    __shared__ int s[256];
    int tid = threadIdx.x;
    int carry = 0;
    for (int base = 0; base < nb; base += 256) {
        int v = (base + tid < nb) ? bsums[base + tid] : 0;
        s[tid] = v; __syncthreads();
        for (int o = 1; o < 256; o <<= 1) {
            int t = (tid >= o) ? s[tid - o] : 0;
            __syncthreads();
            s[tid] += t;
            __syncthreads();
        }
        if (base + tid < nb) boffs[base + tid] = carry + s[tid] - v;
        __syncthreads();
        carry += s[255];
        __syncthreads();
    }
    if (tid == 0) offs[N] = carry;
}

__global__ __launch_bounds__(256) void scan3_kernel(int* __restrict__ offs,
                                                    const int* __restrict__ boffs, int N) {
    int i = blockIdx.x * 256 + threadIdx.x;
    if (i < N) offs[i] += boffs[i >> 8];
}

// ---------------- MFMA GEMM 1: fp32 A -> bf16 Y -----------------------------
__global__ __launch_bounds__(256) void gemm1_mfma(
    const float* __restrict__ X, const ushort_t* __restrict__ Wp,
    const float* __restrict__ bias, ushort_t* __restrict__ Ybf, int N)
{
    const int wave = threadIdx.x >> 6;
    const int lane = threadIdx.x & 63;
    const int quad = lane >> 4;
    const int l16  = lane & 15;
    const int r0   = blockIdx.x * 128 + wave * 32;

    float4v acc[2][8];
    #pragma unroll
    for (int cg = 0; cg < 8; ++cg) {
        float bv = bias[cg * 16 + l16];
        float4v b4 = {bv, bv, bv, bv};
        acc[0][cg] = b4; acc[1][cg] = b4;
    }

    const short8* wp8 = (const short8*)Wp;

    #pragma unroll
    for (int kb = 0; kb < 4; ++kb) {
        const int k0 = kb * 32 + quad * 8;
        short8 a[2];
        #pragma unroll
        for (int rb = 0; rb < 2; ++rb) {
            int row = r0 + rb * 16 + l16;
            if (row >= N) row = N - 1;
            const float* p = &X[(size_t)row * D + k0];
            float4 x0 = *(const float4*)p;
            float4 x1 = *(const float4*)(p + 4);
            short8 s;
            s[0] = (short)f2bf(x0.x); s[1] = (short)f2bf(x0.y);
            s[2] = (short)f2bf(x0.z); s[3] = (short)f2bf(x0.w);
            s[4] = (short)f2bf(x1.x); s[5] = (short)f2bf(x1.y);
            s[6] = (short)f2bf(x1.z); s[7] = (short)f2bf(x1.w);
            a[rb] = s;
        }
        #pragma unroll
        for (int cg = 0; cg < 8; ++cg) {
            short8 b = wp8[(kb * 8 + cg) * 64 + lane];
            acc[0][cg] = __builtin_amdgcn_mfma_f32_16x16x32_bf16(a[0], b, acc[0][cg], 0, 0, 0);
            acc[1][cg] = __builtin_amdgcn_mfma_f32_16x16x32_bf16(a[1], b, acc[1][cg], 0, 0, 0);
        }
    }

    #pragma unroll
    for (int rb = 0; rb < 2; ++rb) {
        int rowb = r0 + rb * 16 + quad * 4;
        #pragma unroll
        for (int cg = 0; cg < 8; ++cg) {
            int col = cg * 16 + l16;
            #pragma unroll
            for (int i = 0; i < 4; ++i) {
                int row = rowb + i;
                if (row < N) Ybf[(size_t)row * D + col] = f2bf(acc[rb][cg][i]);
            }
        }
    }
}

// ---------------- MFMA GEMM 2: bf16 A0/A1 -> fp32 Y + bf16 copy -------------
__global__ __launch_bounds__(256) void gemm2_mfma(
    const ushort_t* __restrict__ A0, const ushort_t* __restrict__ A1,
    const ushort_t* __restrict__ Wp, const float* __restrict__ bias,
    float* __restrict__ Yf, ushort_t* __restrict__ Ybf, int N)
{
    const int wave = threadIdx.x >> 6;
    const int lane = threadIdx.x & 63;
    const int quad = lane >> 4;
    const int l16  = lane & 15;
    const int r0   = blockIdx.x * 128 + wave * 32;

    float4v acc[2][8];
    #pragma unroll
    for (int cg = 0; cg < 8; ++cg) {
        float bv = bias[cg * 16 + l16];
        float4v b4 = {bv, bv, bv, bv};
        acc[0][cg] = b4; acc[1][cg] = b4;
    }

    const short8* wp8 = (const short8*)Wp;

    #pragma unroll
    for (int kb = 0; kb < 8; ++kb) {
        const ushort_t* __restrict__ A = (kb < 4) ? A0 : A1;
        const int k0 = (kb & 3) * 32 + quad * 8;
        short8 a[2];
        #pragma unroll
        for (int rb = 0; rb < 2; ++rb) {
            int row = r0 + rb * 16 + l16;
            if (row >= N) row = N - 1;
            a[rb] = *(const short8*)&A[(size_t)row * D + k0];
        }
        #pragma unroll
        for (int cg = 0; cg < 8; ++cg) {
            short8 b = wp8[(kb * 8 + cg) * 64 + lane];
            acc[0][cg] = __builtin_amdgcn_mfma_f32_16x16x32_bf16(a[0], b, acc[0][cg], 0, 0, 0);
            acc[1][cg] = __builtin_amdgcn_mfma_f32_16x16x32_bf16(a[1], b, acc[1][cg], 0, 0, 0);
        }
    }

    #pragma unroll
    for (int rb = 0; rb < 2; ++rb) {
        int rowb = r0 + rb * 16 + quad * 4;
        #pragma unroll
        for (int cg = 0; cg < 8; ++cg) {
            int col = cg * 16 + l16;
            #pragma unroll
            for (int i = 0; i < 4; ++i) {
                int row = rowb + i;
                if (row < N) {
                    float v = acc[rb][cg][i];
                    Yf[(size_t)row * 256 + col] = v;
                    Ybf[(size_t)row * D + col] = f2bf(v);
                }
            }
        }
    }
}

// ---------------- gather-sum over CSR (bf16 msg), quad-split ---------------
__global__ __launch_bounds__(256) void gather_bf(
    const ushort_t* __restrict__ msg,            // [N][128] bf16
    const int* __restrict__ offs, const int* __restrict__ bsrc,
    ushort_t* __restrict__ aggB,                 // bf16 out [N][128], or null
    float* __restrict__ aggF,                    // fp32 out (stride 256), or null
    int N)
{
    int node = (blockIdx.x * 256 + threadIdx.x) >> 6;
    int lane = threadIdx.x & 63;
    if (node >= N) return;
    const int quad = lane >> 4;
    const int c16  = lane & 15;
    int beg = offs[node], end = offs[node + 1];

    float ax[4] = {0.f, 0.f, 0.f, 0.f};
    float ay[4] = {0.f, 0.f, 0.f, 0.f};
    const uint4* mp = (const uint4*)msg;         // 16 uint4 per row

    for (int base = beg; base < end; base += 64) {
        int cnt = end - base; if (cnt > 64) cnt = 64;
        int sidx = bsrc[base + (lane < cnt ? lane : cnt - 1)];
        for (int j0 = 0; j0 < cnt; j0 += 16) {
            #pragma unroll
            for (int t = 0; t < 4; ++t) {
                int e  = j0 + t * 4 + quad;
                int ec = (e < cnt) ? e : cnt - 1;
                int s  = __shfl(sidx, ec, 64);
                uint4 u = mp[(size_t)s * 16 + c16];
                if (e < cnt) {
                    ax[0] += bflo(u.x); ay[0] += bfhi(u.x);
                    ax[1] += bflo(u.y); ay[1] += bfhi(u.y);
                    ax[2] += bflo(u.z); ay[2] += bfhi(u.z);
                    ax[3] += bflo(u.w); ay[3] += bfhi(u.w);
                }
            }
        }
    }

    #pragma unroll
    for (int k = 0; k < 4; ++k) {
        ax[k] += __shfl_xor(ax[k], 16, 64);
        ax[k] += __shfl_xor(ax[k], 32, 64);
        ay[k] += __shfl_xor(ay[k], 16, 64);
        ay[k] += __shfl_xor(ay[k], 32, 64);
    }

    if (quad == 0) {
        if (aggB) {
            uint4 o;
            o.x = (uint_t)f2bf(ax[0]) | ((uint_t)f2bf(ay[0]) << 16);
            o.y = (uint_t)f2bf(ax[1]) | ((uint_t)f2bf(ay[1]) << 16);
            o.z = (uint_t)f2bf(ax[2]) | ((uint_t)f2bf(ay[2]) << 16);
            o.w = (uint_t)f2bf(ax[3]) | ((uint_t)f2bf(ay[3]) << 16);
            ((uint4*)aggB)[(size_t)node * 16 + c16] = o;
        } else {
            float4 w0 = {ax[0], ay[0], ax[1], ay[1]};
            float4 w1 = {ax[2], ay[2], ax[3], ay[3]};
            float* p = &aggF[(size_t)node * 256 + c16 * 8];
            *(float4*)p = w0;
            *(float4*)(p + 4) = w1;
        }
    }
}

// ---------------------------------------------------------------------------
extern "C" void kernel_launch(void* const* d_in, const int* in_sizes, int n_in,
                              void* d_out, int out_size, void* d_ws, size_t ws_size,
                              hipStream_t stream) {
    const float* features = (const float*)d_in[0];
    const int*   src      = (const int*)d_in[1];
    const int*   dst      = (const int*)d_in[2];
    const float* W1       = (const float*)d_in[3];
    const float* b1       = (const float*)d_in[4];
    const float* W2       = (const float*)d_in[5];
    const float* b2       = (const float*)d_in[6];
    float* out = (float*)d_out;

    const int N = in_sizes[0] / D;   // 50000
    const int E = in_sizes[1];       // 800000

    // ws carve-up
    ushort_t* m1bf   = (ushort_t*)d_ws;                 // N*D
    ushort_t* agg1bf = m1bf + (size_t)N * D;            // N*D
    ushort_t* m2bf   = agg1bf + (size_t)N * D;          // N*D
    ushort_t* W1p    = m2bf + (size_t)N * D;            // 16384
    ushort_t* W2p    = W1p + 16384;                     // 32768
    int* qh    = (int*)(W2p + 32768);                   // 8 counters, stride 32
    int* qf    = qh + 256;                              // 8 counters, stride 32
    int* deg   = qf + 256;                              // N
    int* cnt   = deg + N;                               // N
    int* offs  = cnt + N;                               // N+1
    int* bsums = offs + N + 1;
    int* boffs = bsums + 1024;
    int* bsrc  = boffs + 1024;

    const int nb = (N + 255) / 256;
    const int gemmBlocks = (N + 127) / 128;
    const int nzero = 512 + 2 * N;                      // qh|qf|deg|cnt

    // pack both W + zero queues/deg/cnt in one launch
    pack_zero<<<(nzero + 255) / 256, 256, 0, stream>>>(W1, W2, W1p, W2p, qh, nzero);

    // CSR by dst (XCD-local hist/fill with work-queue + stealing)
    hist_xcd<<<1024, 256, 0, stream>>>(dst, deg, qh, E, N);
    scan1_kernel<<<nb, 256, 0, stream>>>(deg, offs, bsums, N);
    scan2_kernel<<<1, 256, 0, stream>>>(bsums, boffs, nb, offs, N);
    scan3_kernel<<<nb, 256, 0, stream>>>(offs, boffs, N);
    fill_xcd<<<1024, 256, 0, stream>>>(src, dst, offs, cnt, bsrc, qf, E, N);

    // layer 1
    gemm1_mfma<<<gemmBlocks, 256, 0, stream>>>(features, W1p, b1, m1bf, N);
    gather_bf<<<(N * 64 + 255) / 256, 256, 0, stream>>>(m1bf, offs, bsrc,
                                                        agg1bf, nullptr, N);
    // layer 2
    gemm2_mfma<<<gemmBlocks, 256, 0, stream>>>(agg1bf, m1bf, W2p, b2,
                                               out + D, m2bf, N);
    gather_bf<<<(N * 64 + 255) / 256, 256, 0, stream>>>(m2bf, offs, bsrc,
                                                        nullptr, out, N);
}

// Round 7
// 214.294 us; speedup vs baseline: 1.3269x; 1.3269x over previous
//
#include <hip/hip_runtime.h>

// ---------------------------------------------------------------------------
// GNN 2-layer via bf16 MFMA + CSR gather (no atomics in hot path).
//   m1 = bf16(X @ W1 + b1)            [MFMA, fp32 acc]
//   agg1 = bf16(seg_sum m1[src])      [gather, quad-split, 16 rows MLP]
//   m2 = [agg1,m1] @ W2 + b2          [MFMA] -> out[:,128:] fp32 + bf16 copy
//   agg2 = seg_sum m2[src]            [gather] -> out[:,:128] fp32
// CSR build = two-level counting sort (binA/B1/B2/C/D): per-block LDS coarse
// histograms + scans -> private write cursors (NO global atomics), coarse
// binning into tmp, then per-bucket LDS fine sort -> bsrc + offs, coalesced.
// ws: m1bf | agg1bf | m2bf | W1p | W2p | mat | bb | offs | tmp(int2) | bsrc
// ---------------------------------------------------------------------------

#define D 128
#define CBLK 256         // coarse-binning blocks (phases A and C)
#define DCAP 8192        // max edges per coarse bucket for LDS path

typedef __attribute__((ext_vector_type(8))) short short8;
typedef __attribute__((ext_vector_type(4))) float float4v;
typedef unsigned short ushort_t;
typedef unsigned int uint_t;

static __device__ __forceinline__ ushort_t f2bf(float f) {
    uint_t u = __builtin_bit_cast(uint_t, f);
    u += 0x7FFFu + ((u >> 16) & 1u);           // RNE
    return (ushort_t)(u >> 16);
}
static __device__ __forceinline__ float bfhi(uint_t u) {
    return __builtin_bit_cast(float, u & 0xFFFF0000u);
}
static __device__ __forceinline__ float bflo(uint_t u) {
    return __builtin_bit_cast(float, u << 16);
}

// ---------------- pack W (B-fragment layout), both weights ------------------
// frag for (kb, cg, lane): 8 bf16 = W[kb*32 + (lane>>4)*8 + j][cg*16 + (lane&15)]
__global__ __launch_bounds__(256) void pack_w(const float* __restrict__ W1,
                                              const float* __restrict__ W2,
                                              ushort_t* __restrict__ W1p,
                                              ushort_t* __restrict__ W2p) {
    const int n1 = 4 * 8 * 64;
    const int n2 = 8 * 8 * 64;
    int t = blockIdx.x * 256 + threadIdx.x;
    if (t >= n1 + n2) return;
    const float* W; ushort_t* Wp; int tt;
    if (t < n1) { W = W1; Wp = W1p; tt = t; }
    else        { W = W2; Wp = W2p; tt = t - n1; }
    int lane = tt & 63, cg = (tt >> 6) & 7, kb = tt >> 9;
    int krow = kb * 32 + (lane >> 4) * 8;
    int col  = cg * 16 + (lane & 15);
    #pragma unroll
    for (int j = 0; j < 8; ++j)
        Wp[(size_t)tt * 8 + j] = f2bf(W[(size_t)(krow + j) * D + col]);
}

// ---------------- CSR build: two-level counting sort ------------------------
// A: per-block coarse histogram (bucket = dst>>8) -> mat[b][c]
__global__ __launch_bounds__(256) void binA(const int* __restrict__ dst,
                                            int* __restrict__ mat, int E, int NB) {
    __shared__ int h[256];
    const int c = blockIdx.x;
    for (int i = threadIdx.x; i < NB; i += 256) h[i] = 0;
    __syncthreads();
    const int chunk = (E + CBLK - 1) / CBLK;
    int e0 = c * chunk, e1 = e0 + chunk; if (e1 > E) e1 = E;
    for (int e = e0 + threadIdx.x; e < e1; e += 256)
        atomicAdd(&h[dst[e] >> 8], 1);
    __syncthreads();
    for (int i = threadIdx.x; i < NB; i += 256)
        mat[i * CBLK + c] = h[i];
}

// B1: bucket totals + exclusive scan -> bb[0..NB] ; offs[N] = E
__global__ __launch_bounds__(256) void binB1(const int* __restrict__ mat,
                                             int* __restrict__ bb,
                                             int* __restrict__ offs,
                                             int E, int N, int NB) {
    __shared__ int s[256];
    int tid = threadIdx.x;
    int v = 0;
    if (tid < NB) {
        const int* row = &mat[tid * CBLK];
        for (int c = 0; c < CBLK; ++c) v += row[c];
    }
    s[tid] = v; __syncthreads();
    for (int o = 1; o < 256; o <<= 1) {
        int t = (tid >= o) ? s[tid - o] : 0;
        __syncthreads();
        s[tid] += t;
        __syncthreads();
    }
    if (tid < NB) bb[tid] = s[tid] - v;
    if (tid == 0) { bb[NB] = E; offs[N] = E; }
}

// B2: per-bucket exclusive scan over block counts -> mat[b][c] = write cursor
__global__ __launch_bounds__(256) void binB2(int* __restrict__ mat,
                                             const int* __restrict__ bb, int NB) {
    __shared__ int s[256];
    int b = blockIdx.x;
    int tid = threadIdx.x;
    int v = mat[b * CBLK + tid];
    s[tid] = v; __syncthreads();
    for (int o = 1; o < 256; o <<= 1) {
        int t = (tid >= o) ? s[tid - o] : 0;
        __syncthreads();
        s[tid] += t;
        __syncthreads();
    }
    mat[b * CBLK + tid] = bb[b] + s[tid] - v;
}

// C: coarse binning -> tmp[(dst,src)] at private (block,bucket) cursors
__global__ __launch_bounds__(256) void binC(const int* __restrict__ src,
                                            const int* __restrict__ dst,
                                            const int* __restrict__ mat,
                                            int2* __restrict__ tmp, int E, int NB) {
    __shared__ int base[256];
    __shared__ int lcnt[256];
    const int c = blockIdx.x;
    for (int i = threadIdx.x; i < NB; i += 256) {
        base[i] = mat[i * CBLK + c];
        lcnt[i] = 0;
    }
    __syncthreads();
    const int chunk = (E + CBLK - 1) / CBLK;
    int e0 = c * chunk, e1 = e0 + chunk; if (e1 > E) e1 = E;
    for (int e = e0 + threadIdx.x; e < e1; e += 256) {
        int d = dst[e];
        int b = d >> 8;
        int p = base[b] + atomicAdd(&lcnt[b], 1);
        int2 pr; pr.x = d; pr.y = src[e];
        tmp[p] = pr;
    }
}

// D: per-bucket fine sort (256 bins) -> offs[node] + bsrc (coalesced out)
__global__ __launch_bounds__(256) void binD(const int2* __restrict__ tmp,
                                            const int* __restrict__ bb,
                                            int* __restrict__ offs,
                                            int* __restrict__ bsrc, int N, int NB) {
    __shared__ int hist[256];
    __shared__ int foff[256];
    __shared__ int cntf[256];
    __shared__ int outS[DCAP];
    const int b = blockIdx.x;
    const int tid = threadIdx.x;
    const int beg = bb[b], end = bb[b + 1];
    const int cnt = end - beg;
    const int n0 = b << 8;

    hist[tid] = 0;
    __syncthreads();
    for (int i = tid; i < cnt; i += 256)
        atomicAdd(&hist[tmp[beg + i].x & 255], 1);
    __syncthreads();
    // exclusive scan of hist -> foff
    int v = hist[tid];
    int s = v;
    __syncthreads();
    hist[tid] = s; __syncthreads();
    for (int o = 1; o < 256; o <<= 1) {
        int t = (tid >= o) ? hist[tid - o] : 0;
        __syncthreads();
        hist[tid] += t;
        __syncthreads();
    }
    foff[tid] = hist[tid] - v;
    cntf[tid] = 0;
    __syncthreads();

    int node = n0 + tid;
    if (node < N) offs[node] = beg + foff[tid];

    if (cnt <= DCAP) {
        for (int i = tid; i < cnt; i += 256) {
            int2 p = tmp[beg + i];
            int f = p.x & 255;
            int pos = foff[f] + atomicAdd(&cntf[f], 1);
            outS[pos] = p.y;
        }
        __syncthreads();
        for (int i = tid; i < cnt; i += 256)
            bsrc[beg + i] = outS[i];
    } else {
        for (int i = tid; i < cnt; i += 256) {
            int2 p = tmp[beg + i];
            int f = p.x & 255;
            int pos = foff[f] + atomicAdd(&cntf[f], 1);
            bsrc[beg + pos] = p.y;
        }
    }
}

// ---------------- MFMA GEMM 1: fp32 A -> bf16 Y -----------------------------
__global__ __launch_bounds__(256) void gemm1_mfma(
    const float* __restrict__ X, const ushort_t* __restrict__ Wp,
    const float* __restrict__ bias, ushort_t* __restrict__ Ybf, int N)
{
    const int wave = threadIdx.x >> 6;
    const int lane = threadIdx.x & 63;
    const int quad = lane >> 4;
    const int l16  = lane & 15;
    const int r0   = blockIdx.x * 128 + wave * 32;

    float4v acc[2][8];
    #pragma unroll
    for (int cg = 0; cg < 8; ++cg) {
        float bv = bias[cg * 16 + l16];
        float4v b4 = {bv, bv, bv, bv};
        acc[0][cg] = b4; acc[1][cg] = b4;
    }

    const short8* wp8 = (const short8*)Wp;

    #pragma unroll
    for (int kb = 0; kb < 4; ++kb) {
        const int k0 = kb * 32 + quad * 8;
        short8 a[2];
        #pragma unroll
        for (int rb = 0; rb < 2; ++rb) {
            int row = r0 + rb * 16 + l16;
            if (row >= N) row = N - 1;
            const float* p = &X[(size_t)row * D + k0];
            float4 x0 = *(const float4*)p;
            float4 x1 = *(const float4*)(p + 4);
            short8 s;
            s[0] = (short)f2bf(x0.x); s[1] = (short)f2bf(x0.y);
            s[2] = (short)f2bf(x0.z); s[3] = (short)f2bf(x0.w);
            s[4] = (short)f2bf(x1.x); s[5] = (short)f2bf(x1.y);
            s[6] = (short)f2bf(x1.z); s[7] = (short)f2bf(x1.w);
            a[rb] = s;
        }
        #pragma unroll
        for (int cg = 0; cg < 8; ++cg) {
            short8 b = wp8[(kb * 8 + cg) * 64 + lane];
            acc[0][cg] = __builtin_amdgcn_mfma_f32_16x16x32_bf16(a[0], b, acc[0][cg], 0, 0, 0);
            acc[1][cg] = __builtin_amdgcn_mfma_f32_16x16x32_bf16(a[1], b, acc[1][cg], 0, 0, 0);
        }
    }

    #pragma unroll
    for (int rb = 0; rb < 2; ++rb) {
        int rowb = r0 + rb * 16 + quad * 4;
        #pragma unroll
        for (int cg = 0; cg < 8; ++cg) {
            int col = cg * 16 + l16;
            #pragma unroll
            for (int i = 0; i < 4; ++i) {
                int row = rowb + i;
                if (row < N) Ybf[(size_t)row * D + col] = f2bf(acc[rb][cg][i]);
            }
        }
    }
}

// ---------------- MFMA GEMM 2: bf16 A0/A1 -> fp32 Y + bf16 copy -------------
__global__ __launch_bounds__(256) void gemm2_mfma(
    const ushort_t* __restrict__ A0, const ushort_t* __restrict__ A1,
    const ushort_t* __restrict__ Wp, const float* __restrict__ bias,
    float* __restrict__ Yf, ushort_t* __restrict__ Ybf, int N)
{
    const int wave = threadIdx.x >> 6;
    const int lane = threadIdx.x & 63;
    const int quad = lane >> 4;
    const int l16  = lane & 15;
    const int r0   = blockIdx.x * 128 + wave * 32;

    float4v acc[2][8];
    #pragma unroll
    for (int cg = 0; cg < 8; ++cg) {
        float bv = bias[cg * 16 + l16];
        float4v b4 = {bv, bv, bv, bv};
        acc[0][cg] = b4; acc[1][cg] = b4;
    }

    const short8* wp8 = (const short8*)Wp;

    #pragma unroll
    for (int kb = 0; kb < 8; ++kb) {
        const ushort_t* __restrict__ A = (kb < 4) ? A0 : A1;
        const int k0 = (kb & 3) * 32 + quad * 8;
        short8 a[2];
        #pragma unroll
        for (int rb = 0; rb < 2; ++rb) {
            int row = r0 + rb * 16 + l16;
            if (row >= N) row = N - 1;
            a[rb] = *(const short8*)&A[(size_t)row * D + k0];
        }
        #pragma unroll
        for (int cg = 0; cg < 8; ++cg) {
            short8 b = wp8[(kb * 8 + cg) * 64 + lane];
            acc[0][cg] = __builtin_amdgcn_mfma_f32_16x16x32_bf16(a[0], b, acc[0][cg], 0, 0, 0);
            acc[1][cg] = __builtin_amdgcn_mfma_f32_16x16x32_bf16(a[1], b, acc[1][cg], 0, 0, 0);
        }
    }

    #pragma unroll
    for (int rb = 0; rb < 2; ++rb) {
        int rowb = r0 + rb * 16 + quad * 4;
        #pragma unroll
        for (int cg = 0; cg < 8; ++cg) {
            int col = cg * 16 + l16;
            #pragma unroll
            for (int i = 0; i < 4; ++i) {
                int row = rowb + i;
                if (row < N) {
                    float v = acc[rb][cg][i];
                    Yf[(size_t)row * 256 + col] = v;
                    Ybf[(size_t)row * D + col] = f2bf(v);
                }
            }
        }
    }
}

// ---------------- gather-sum over CSR (bf16 msg), quad-split ---------------
__global__ __launch_bounds__(256) void gather_bf(
    const ushort_t* __restrict__ msg,            // [N][128] bf16
    const int* __restrict__ offs, const int* __restrict__ bsrc,
    ushort_t* __restrict__ aggB,                 // bf16 out [N][128], or null
    float* __restrict__ aggF,                    // fp32 out (stride 256), or null
    int N)
{
    int node = (blockIdx.x * 256 + threadIdx.x) >> 6;
    int lane = threadIdx.x & 63;
    if (node >= N) return;
    const int quad = lane >> 4;
    const int c16  = lane & 15;
    int beg = offs[node], end = offs[node + 1];

    float ax[4] = {0.f, 0.f, 0.f, 0.f};
    float ay[4] = {0.f, 0.f, 0.f, 0.f};
    const uint4* mp = (const uint4*)msg;         // 16 uint4 per row

    for (int base = beg; base < end; base += 64) {
        int cnt = end - base; if (cnt > 64) cnt = 64;
        int sidx = bsrc[base + (lane < cnt ? lane : cnt - 1)];
        for (int j0 = 0; j0 < cnt; j0 += 16) {
            #pragma unroll
            for (int t = 0; t < 4; ++t) {
                int e  = j0 + t * 4 + quad;
                int ec = (e < cnt) ? e : cnt - 1;
                int s  = __shfl(sidx, ec, 64);
                uint4 u = mp[(size_t)s * 16 + c16];
                if (e < cnt) {
                    ax[0] += bflo(u.x); ay[0] += bfhi(u.x);
                    ax[1] += bflo(u.y); ay[1] += bfhi(u.y);
                    ax[2] += bflo(u.z); ay[2] += bfhi(u.z);
                    ax[3] += bflo(u.w); ay[3] += bfhi(u.w);
                }
            }
        }
    }

    #pragma unroll
    for (int k = 0; k < 4; ++k) {
        ax[k] += __shfl_xor(ax[k], 16, 64);
        ax[k] += __shfl_xor(ax[k], 32, 64);
        ay[k] += __shfl_xor(ay[k], 16, 64);
        ay[k] += __shfl_xor(ay[k], 32, 64);
    }

    if (quad == 0) {
        if (aggB) {
            uint4 o;
            o.x = (uint_t)f2bf(ax[0]) | ((uint_t)f2bf(ay[0]) << 16);
            o.y = (uint_t)f2bf(ax[1]) | ((uint_t)f2bf(ay[1]) << 16);
            o.z = (uint_t)f2bf(ax[2]) | ((uint_t)f2bf(ay[2]) << 16);
            o.w = (uint_t)f2bf(ax[3]) | ((uint_t)f2bf(ay[3]) << 16);
            ((uint4*)aggB)[(size_t)node * 16 + c16] = o;
        } else {
            float4 w0 = {ax[0], ay[0], ax[1], ay[1]};
            float4 w1 = {ax[2], ay[2], ax[3], ay[3]};
            float* p = &aggF[(size_t)node * 256 + c16 * 8];
            *(float4*)p = w0;
            *(float4*)(p + 4) = w1;
        }
    }
}

// ---------------------------------------------------------------------------
extern "C" void kernel_launch(void* const* d_in, const int* in_sizes, int n_in,
                              void* d_out, int out_size, void* d_ws, size_t ws_size,
                              hipStream_t stream) {
    const float* features = (const float*)d_in[0];
    const int*   src      = (const int*)d_in[1];
    const int*   dst      = (const int*)d_in[2];
    const float* W1       = (const float*)d_in[3];
    const float* b1       = (const float*)d_in[4];
    const float* W2       = (const float*)d_in[5];
    const float* b2       = (const float*)d_in[6];
    float* out = (float*)d_out;

    const int N = in_sizes[0] / D;   // 50000
    const int E = in_sizes[1];       // 800000
    const int NB = (N + 255) >> 8;   // 196 coarse buckets (<=256 required)

    // ws carve-up
    ushort_t* m1bf   = (ushort_t*)d_ws;                 // N*D
    ushort_t* agg1bf = m1bf + (size_t)N * D;            // N*D
    ushort_t* m2bf   = agg1bf + (size_t)N * D;          // N*D
    ushort_t* W1p    = m2bf + (size_t)N * D;            // 16384
    ushort_t* W2p    = W1p + 16384;                     // 32768
    int*  mat  = (int*)(W2p + 32768);                   // NB*CBLK
    int*  bb   = mat + (size_t)NB * CBLK;               // NB+1
    int*  offs = bb + NB + 1;                           // N+1
    int2* tmp  = (int2*)(offs + N + 1);                 // E pairs
    int*  bsrc = (int*)(tmp + (size_t)E);               // E

    const int gemmBlocks = (N + 127) / 128;

    // pack both W
    pack_w<<<(12 * 8 * 64 + 255) / 256, 256, 0, stream>>>(W1, W2, W1p, W2p);

    // CSR by dst: two-level counting sort (no global atomics)
    binA <<<CBLK, 256, 0, stream>>>(dst, mat, E, NB);
    binB1<<<1,    256, 0, stream>>>(mat, bb, offs, E, N, NB);
    binB2<<<NB,   256, 0, stream>>>(mat, bb, NB);
    binC <<<CBLK, 256, 0, stream>>>(src, dst, mat, tmp, E, NB);
    binD <<<NB,   256, 0, stream>>>(tmp, bb, offs, bsrc, N, NB);

    // layer 1
    gemm1_mfma<<<gemmBlocks, 256, 0, stream>>>(features, W1p, b1, m1bf, N);
    gather_bf<<<(N * 64 + 255) / 256, 256, 0, stream>>>(m1bf, offs, bsrc,
                                                        agg1bf, nullptr, N);
    // layer 2
    gemm2_mfma<<<gemmBlocks, 256, 0, stream>>>(agg1bf, m1bf, W2p, b2,
                                               out + D, m2bf, N);
    gather_bf<<<(N * 64 + 255) / 256, 256, 0, stream>>>(m2bf, offs, bsrc,
                                                        nullptr, out, N);
}